// Round 1
// baseline (572.207 us; speedup 1.0000x reference)
//
#include <hip/hip_runtime.h>
#include <math.h>

#define B_    16
#define P_    10000
#define NB_   10
#define KBTOT 313      // ceil(P_/32) k-blocks of 32
#define KBPAD 328      // padded k-block count (zero-filled tail)
#define NSMAX 16       // max K-splits

typedef __attribute__((ext_vector_type(8))) short bf16x8;   // 8 bf16 (4 VGPRs)
typedef __attribute__((ext_vector_type(4))) float f32x4;    // MFMA accumulator

static __device__ __forceinline__ unsigned short f2bf(float f) {
    // RNE float -> bf16 bits
    unsigned u = __float_as_uint(f);
    u += 0x7fffu + ((u >> 16) & 1u);
    return (unsigned short)(u >> 16);
}

// ---------------- Kernel 1: T = R(logr) @ S ----------------
__global__ __launch_bounds__(256) void ftoT_kernel(const float* __restrict__ f,
                                                   float* __restrict__ Tm2) {
    int t = blockIdx.x * blockDim.x + threadIdx.x;
    if (t >= B_ * P_) return;
    int p = t >> 4, b = t & 15;
    const float* fp = f + ((size_t)b * P_ + p) * 9;
    float x = fp[0], y = fp[1], z = fp[2];
    float s3 = fp[3], s4 = fp[4], s5 = fp[5], s6 = fp[6], s7 = fp[7], s8 = fp[8];
    float th2 = x * x + y * y + z * z;
    float R00, R01, R02, R10, R11, R12, R20, R21, R22;
    if (th2 == 0.0f) {
        R00 = 1; R01 = 0; R02 = 0; R10 = 0; R11 = 1; R12 = 0; R20 = 0; R21 = 0; R22 = 1;
    } else {
        float theta = sqrtf(th2);
        float inv = 1.0f / theta;
        float kx = x * inv, ky = y * inv, kz = z * inv;
        float st = sinf(theta);
        float omc = 1.0f - cosf(theta);
        R00 = 1.0f - omc * (kx * kx + ky * ky);
        R01 = kx * st - omc * (ky * kz);
        R02 = ky * st + omc * (kx * kz);
        R10 = -kx * st - omc * (ky * kz);
        R11 = 1.0f - omc * (kx * kx + kz * kz);
        R12 = kz * st - omc * (kx * ky);
        R20 = -ky * st + omc * (kx * kz);
        R21 = -kz * st - omc * (kx * ky);
        R22 = 1.0f - omc * (ky * ky + kz * kz);
    }
    float* o = Tm2 + (size_t)t * 12;
    o[0] = R00 * s3 + R01 * s4 + R02 * s5;
    o[1] = R00 * s4 + R01 * s6 + R02 * s7;
    o[2] = R00 * s5 + R01 * s7 + R02 * s8;
    o[3] = R10 * s3 + R11 * s4 + R12 * s5;
    o[4] = R10 * s4 + R11 * s6 + R12 * s7;
    o[5] = R10 * s5 + R11 * s7 + R12 * s8;
    o[6] = R20 * s3 + R21 * s4 + R22 * s5;
    o[7] = R20 * s4 + R21 * s6 + R22 * s7;
    o[8] = R20 * s5 + R21 * s7 + R22 * s8;
    o[9] = 0.0f; o[10] = 0.0f; o[11] = 0.0f;
}

// ------- Kernel 2: bvec + pack into MFMA B-fragment layout (bf16) -------
__global__ __launch_bounds__(256) void bvec_kernel(const float* __restrict__ Tm2,
                                                   const int* __restrict__ nb,
                                                   const float* __restrict__ vdiff,
                                                   unsigned short* __restrict__ Bf) {
    int tid = threadIdx.x;
    int bl = tid & 15, pl = tid >> 4;
    int p = blockIdx.x * 16 + pl;
    if (p >= P_) return;

    const float4* Tow = (const float4*)(Tm2 + ((size_t)p * 16 + bl) * 12);
    float4 o0 = Tow[0], o1 = Tow[1], o2 = Tow[2];

    float a0 = 0, a1 = 0, a2 = 0, vs0 = 0, vs1 = 0, vs2 = 0;
#pragma unroll
    for (int n = 0; n < NB_; n++) {
        int idx = nb[p * NB_ + n];
        const float* vd = vdiff + ((size_t)p * NB_ + n) * 3;
        float v0 = vd[0], v1 = vd[1], v2 = vd[2];
        vs0 += v0; vs1 += v1; vs2 += v2;
        if (idx > 0) {
            const float4* Tp = (const float4*)(Tm2 + ((size_t)(idx - 1) * 16 + bl) * 12);
            float4 q0 = Tp[0], q1 = Tp[1], q2 = Tp[2];
            a0 += q0.x * v0 + q0.y * v1 + q0.z * v2;
            a1 += q0.w * v0 + q1.x * v1 + q1.y * v2;
            a2 += q1.z * v0 + q1.w * v1 + q2.x * v2;
        }
    }
    a0 += o0.x * vs0 + o0.y * vs1 + o0.z * vs2;
    a1 += o0.w * vs0 + o1.x * vs1 + o1.y * vs2;
    a2 += o1.z * vs0 + o1.w * vs1 + o2.x * vs2;

    int kb = p >> 5, ii = p & 7, quad = (p >> 3) & 3;
    float vals[3] = {a0, a1, a2};
#pragma unroll
    for (int d = 0; d < 3; d++) {
        int j = bl * 3 + d;
        int t = j >> 4;
        int ln = quad * 16 + (j & 15);
        Bf[(((size_t)kb * 3 + t) * 64 + ln) * 8 + ii] = f2bf(vals[d]);
    }
}

// ------- Kernel 3: MFMA GEMM, latency-hiding rewrite. -------
// Wave = 16 rows x 48 cols, no LDS. Branchless main loop over the
// guaranteed-in-bounds region (kb < 312), 2-slot register software pipeline
// so ~10 VMEM ops stay in flight per wave. Guarded tail (<=8 iters) only in
// the last K-split.
static __device__ __forceinline__ void slot_load(const float* __restrict__ ap,
                                                 const bf16x8* __restrict__ Bv,
                                                 int l, int kb,
                                                 float4& a0, float4& a1,
                                                 bf16x8& b0, bf16x8& b1, bf16x8& b2) {
    const float4* p = (const float4*)(ap + (size_t)kb * 32);
    a0 = p[0]; a1 = p[1];
    size_t bo = (size_t)kb * 192 + l;
    b0 = Bv[bo]; b1 = Bv[bo + 64]; b2 = Bv[bo + 128];
}

static __device__ __forceinline__ void slot_mfma(const float4& a0, const float4& a1,
                                                 const bf16x8& b0, const bf16x8& b1,
                                                 const bf16x8& b2,
                                                 f32x4& acc0, f32x4& acc1, f32x4& acc2) {
    bf16x8 a;
    a[0] = (short)f2bf(a0.x); a[1] = (short)f2bf(a0.y);
    a[2] = (short)f2bf(a0.z); a[3] = (short)f2bf(a0.w);
    a[4] = (short)f2bf(a1.x); a[5] = (short)f2bf(a1.y);
    a[6] = (short)f2bf(a1.z); a[7] = (short)f2bf(a1.w);
    acc0 = __builtin_amdgcn_mfma_f32_16x16x32_bf16(a, b0, acc0, 0, 0, 0);
    acc1 = __builtin_amdgcn_mfma_f32_16x16x32_bf16(a, b1, acc1, 0, 0, 0);
    acc2 = __builtin_amdgcn_mfma_f32_16x16x32_bf16(a, b2, acc2, 0, 0, 0);
}

__global__ __launch_bounds__(256, 4) void gemm_mfma(const float* __restrict__ recon,
                                                    const unsigned short* __restrict__ Bf,
                                                    float* __restrict__ part, int KBC) {
    int l = threadIdx.x & 63;
    int w = threadIdx.x >> 6;
    int r0 = (blockIdx.x * 4 + w) * 16;
    if (r0 >= P_) return;
    int y = blockIdx.y;
    int kb0 = y * KBC;
    int kbend = kb0 + KBC; if (kbend > 320) kbend = 320;
    int kbf = kbend < 312 ? kbend : 312;    // full region: all quads in-bounds
    if (kbf < kb0) kbf = kb0;
    int n = l & 15, quad = l >> 4;
    const float* ap = recon + (size_t)(r0 + n) * P_ + quad * 8;
    const bf16x8* Bv = (const bf16x8*)Bf;

    f32x4 acc0 = {0, 0, 0, 0}, acc1 = {0, 0, 0, 0}, acc2 = {0, 0, 0, 0};

    int nfull = kbf - kb0;                   // multiple of 4 by construction (or 0)
    if (nfull >= 2) {
        float4 s0a0, s0a1, s1a0, s1a1;
        bf16x8 s0b0, s0b1, s0b2, s1b0, s1b1, s1b2;
        slot_load(ap, Bv, l, kb0,     s0a0, s0a1, s0b0, s0b1, s0b2);
        slot_load(ap, Bv, l, kb0 + 1, s1a0, s1a1, s1b0, s1b1, s1b2);
        for (int kb = kb0 + 2; kb + 1 < kbf; kb += 2) {
            slot_mfma(s0a0, s0a1, s0b0, s0b1, s0b2, acc0, acc1, acc2);
            slot_load(ap, Bv, l, kb,     s0a0, s0a1, s0b0, s0b1, s0b2);
            slot_mfma(s1a0, s1a1, s1b0, s1b1, s1b2, acc0, acc1, acc2);
            slot_load(ap, Bv, l, kb + 1, s1a0, s1a1, s1b0, s1b1, s1b2);
        }
        slot_mfma(s0a0, s0a1, s0b0, s0b1, s0b2, acc0, acc1, acc2);
        slot_mfma(s1a0, s1a1, s1b0, s1b1, s1b2, acc0, acc1, acc2);
    }

    // tail (last split only): per-lane k guard, <=8 iterations
    for (int kb = kbf; kb < kbend; ++kb) {
        int k = kb * 32 + quad * 8;
        bf16x8 a;
        if (k < P_) {
            const float4* apk = (const float4*)(recon + (size_t)(r0 + n) * P_ + k);
            float4 x0 = apk[0], x1 = apk[1];
            a[0] = (short)f2bf(x0.x); a[1] = (short)f2bf(x0.y);
            a[2] = (short)f2bf(x0.z); a[3] = (short)f2bf(x0.w);
            a[4] = (short)f2bf(x1.x); a[5] = (short)f2bf(x1.y);
            a[6] = (short)f2bf(x1.z); a[7] = (short)f2bf(x1.w);
        } else {
            a = (bf16x8)0;
        }
        size_t bo = (size_t)kb * 192 + l;
        bf16x8 b0 = Bv[bo], b1 = Bv[bo + 64], b2 = Bv[bo + 128];
        acc0 = __builtin_amdgcn_mfma_f32_16x16x32_bf16(a, b0, acc0, 0, 0, 0);
        acc1 = __builtin_amdgcn_mfma_f32_16x16x32_bf16(a, b1, acc1, 0, 0, 0);
        acc2 = __builtin_amdgcn_mfma_f32_16x16x32_bf16(a, b2, acc2, 0, 0, 0);
    }

    // C/D: col = lane&15, row = (lane>>4)*4 + reg  -> float4 store per tile
    float* base = part + (size_t)y * (48 * P_);
    int rs = r0 + quad * 4;
    f32x4 accs[3] = {acc0, acc1, acc2};
#pragma unroll
    for (int t = 0; t < 3; t++) {
        int j = t * 16 + n;
        float4 st = make_float4(accs[t][0], accs[t][1], accs[t][2], accs[t][3]);
        *(float4*)(base + (size_t)j * P_ + rs) = st;
    }
}

// ------- Kernel 4: out[b][r][d] = sum_y part[y][j=b*3+d][r] -------
__global__ __launch_bounds__(256) void reduce_kernel(const float* __restrict__ part,
                                                     float* __restrict__ out, int NS) {
    int i = blockIdx.x * blockDim.x + threadIdx.x;
    if (i >= 48 * P_) return;
    float s = 0.0f;
    for (int z = 0; z < NS; z++) s += part[(size_t)z * (48 * P_) + i];
    int j = i / P_;
    int r = i - j * P_;
    int b = j / 3;
    int d = j - 3 * b;
    out[((size_t)b * P_ + r) * 3 + d] = s;
}

extern "C" void kernel_launch(void* const* d_in, const int* in_sizes, int n_in,
                              void* d_out, int out_size, void* d_ws, size_t ws_size,
                              hipStream_t stream) {
    const float* geo   = (const float*)d_in[0];
    const int*   nb    = (const int*)d_in[1];
    const float* recon = (const float*)d_in[2];
    const float* vdiff = (const float*)d_in[3];
    float* out = (float*)d_out;

    // workspace partition
    const size_t Tm2F = (size_t)B_ * P_ * 12;                 // 7.68 MB
    const size_t BfU  = (size_t)KBPAD * 3 * 64 * 8;           // 503808 ushorts
    const size_t BfF  = (BfU + 1) / 2;                        // in float units
    float*          Tm2  = (float*)d_ws;
    unsigned short* Bf   = (unsigned short*)(Tm2 + Tm2F);
    float*          part = Tm2 + Tm2F + BfF;

    // adaptive K-split (each partial slab = 48*P_ floats = 1.92 MB)
    size_t ws_floats = ws_size / 4;
    size_t used = Tm2F + BfF;
    size_t avail = (ws_floats > used) ? (ws_floats - used) : 0;
    int NS = (int)(avail / ((size_t)48 * P_));
    if (NS > NSMAX) NS = NSMAX;
    if (NS < 1) NS = 1;
    int KBC = (320 + NS - 1) / NS;      // k-blocks per split
    KBC = (KBC + 3) & ~3;               // multiple of 4: keeps pipeline trip count even
    int NSeff = (320 + KBC - 1) / KBC;  // actual splits launched (<= NS)

    hipMemsetAsync(Bf, 0, BfU * sizeof(unsigned short), stream);
    int BP = B_ * P_;
    hipLaunchKernelGGL(ftoT_kernel, dim3((BP + 255) / 256), dim3(256), 0, stream, geo, Tm2);
    hipLaunchKernelGGL(bvec_kernel, dim3((P_ + 15) / 16), dim3(256), 0, stream,
                       Tm2, nb, vdiff, Bf);
    hipLaunchKernelGGL(gemm_mfma, dim3((P_ + 63) / 64, NSeff), dim3(256), 0, stream,
                       recon, Bf, part, KBC);
    hipLaunchKernelGGL(reduce_kernel, dim3((48 * P_ + 255) / 256), dim3(256), 0, stream,
                       part, out, NSeff);
}